// Round 3
// baseline (2175.965 us; speedup 1.0000x reference)
//
#include <hip/hip_runtime.h>
#include <hip/hip_bf16.h>
#include <stdint.h>

// Problem dims (hardcoded from reference):
// B=256, T=100, D=2*34*34=2312, H=1000, O=10.  ALL tensors fp32.
#define T_STEPS 100
#define B_SZ    256
#define D_IN    2312
#define H_SZ    1000
#define O_SZ    10

// ---------------------------------------------------------------------------
// Phase 1: cur1[m][n] = sum_k A[m][k] * W[n][k] + b1[n]   (all fp32)
// Classic LDS-tiled fp32 GEMM: 64x64 tile, BK=16, 256 threads, 4x4 per thread.
// K tail (2312 = 144*16 + 8) handled by zero-padding LDS via the k-guard.
// ---------------------------------------------------------------------------
__global__ __launch_bounds__(256)
void gemm1_f32(const float* __restrict__ A,   // [Mc, D_IN]
               const float* __restrict__ W,   // [H_SZ, D_IN]
               const float* __restrict__ b1,  // [H_SZ]
               float* __restrict__ C,         // [Mc, H_SZ]
               int Mc)
{
  __shared__ float sA[16][64];   // sA[k][m]
  __shared__ float sB[16][64];   // sB[k][n] = W[n][k]

  const int tid = threadIdx.x;
  const int m0  = blockIdx.x * 64;
  const int n0  = blockIdx.y * 64;
  const int tm  = tid & 15;       // 16x16 thread grid
  const int tn  = tid >> 4;

  // Cooperative load mapping: thread -> row lr (0..63), float4 at k-offset lk.
  const int lr = tid >> 2;
  const int lk = (tid & 3) * 4;

  const bool avalid = (m0 + lr < Mc);
  const int  am = avalid ? (m0 + lr) : (Mc - 1);          // clamped (read-safe)
  const int  wn = (n0 + lr < H_SZ) ? (n0 + lr) : (H_SZ - 1);
  const float* Arow = A + (size_t)am * D_IN + lk;
  const float* Wrow = W + (size_t)wn * D_IN + lk;

  float acc[4][4];
  #pragma unroll
  for (int i = 0; i < 4; ++i)
    #pragma unroll
    for (int j = 0; j < 4; ++j) acc[i][j] = 0.f;

  for (int k0 = 0; k0 < D_IN; k0 += 16) {
    float4 av = {0.f, 0.f, 0.f, 0.f}, wv = {0.f, 0.f, 0.f, 0.f};
    if (k0 + lk < D_IN) {                   // D_IN%4==0 -> full float4 in-bounds
      if (avalid) av = *reinterpret_cast<const float4*>(Arow + k0);
      wv = *reinterpret_cast<const float4*>(Wrow + k0);
    }
    __syncthreads();                        // previous iter's LDS reads done
    sA[lk + 0][lr] = av.x; sA[lk + 1][lr] = av.y;
    sA[lk + 2][lr] = av.z; sA[lk + 3][lr] = av.w;
    sB[lk + 0][lr] = wv.x; sB[lk + 1][lr] = wv.y;
    sB[lk + 2][lr] = wv.z; sB[lk + 3][lr] = wv.w;
    __syncthreads();
    #pragma unroll
    for (int k = 0; k < 16; ++k) {
      const float4 a4 = *reinterpret_cast<const float4*>(&sA[k][tm * 4]);
      const float4 b4 = *reinterpret_cast<const float4*>(&sB[k][tn * 4]);
      const float a[4] = {a4.x, a4.y, a4.z, a4.w};
      const float b[4] = {b4.x, b4.y, b4.z, b4.w};
      #pragma unroll
      for (int i = 0; i < 4; ++i)
        #pragma unroll
        for (int j = 0; j < 4; ++j)
          acc[i][j] += a[i] * b[j];
    }
  }

  #pragma unroll
  for (int j = 0; j < 4; ++j) {
    const int col = n0 + tn * 4 + j;
    if (col < H_SZ) {
      const float bias = b1[col];
      #pragma unroll
      for (int i = 0; i < 4; ++i) {
        const int row = m0 + tm * 4 + i;
        if (row < Mc)
          C[(size_t)row * H_SZ + col] = acc[i][j] + bias;
      }
    }
  }
}

// ---------------------------------------------------------------------------
// Phase 2a: layer-1 LIF scan. One thread per (b,h) chain.
// mem = beta*mem + cur1 - spk_prev ; spk = (mem > 1).  Spikes 0/1 exact in bf16.
// ---------------------------------------------------------------------------
__global__ __launch_bounds__(256)
void scan1_kernel(const float* __restrict__ cur1,     // [Bc, T, H] fp32
                  const float* __restrict__ beta_p,
                  __hip_bfloat16* __restrict__ spk1)  // [Bc, T, H] bf16 (0/1)
{
  const int h = blockIdx.x * 256 + threadIdx.x;
  const int b = blockIdx.y;
  if (h >= H_SZ) return;
  const float beta = beta_p[0];
  const float* c    = cur1 + (size_t)b * T_STEPS * H_SZ + h;
  __hip_bfloat16* s = spk1 + (size_t)b * T_STEPS * H_SZ + h;
  float mem = 0.f, spk = 0.f;
  #pragma unroll 4
  for (int t = 0; t < T_STEPS; ++t) {
    mem = beta * mem + c[(size_t)t * H_SZ] - spk;
    spk = (mem > 1.0f) ? 1.0f : 0.0f;
    s[(size_t)t * H_SZ] = __float2bfloat16(spk);
  }
}

// ---------------------------------------------------------------------------
// Phase 2b: cur2[m][o] = sum_h spk1[m][h] * w2[o][h].  Wave per row m.
// Spikes are exactly 0/1 -> accumulate w2 where spike!=0 (exact).
// ---------------------------------------------------------------------------
__global__ __launch_bounds__(256)
void gemm2_kernel(const __hip_bfloat16* __restrict__ spk1, // [Mc, H]
                  const float* __restrict__ w2,            // [O, H] fp32
                  float* __restrict__ cur2)                // [Mc, O] slice
{
  const int wid  = threadIdx.x >> 6;
  const int lane = threadIdx.x & 63;
  const int m    = blockIdx.x * 4 + wid;

  float acc[O_SZ];
  #pragma unroll
  for (int o = 0; o < O_SZ; ++o) acc[o] = 0.f;

  const __hip_bfloat16* row = spk1 + (size_t)m * H_SZ;
  #pragma unroll
  for (int it = 0; it < 16; ++it) {
    const int h = it * 64 + lane;
    if (h < H_SZ) {
      const float s = __bfloat162float(row[h]);
      if (s != 0.f) {
        #pragma unroll
        for (int o = 0; o < O_SZ; ++o)
          acc[o] += w2[o * H_SZ + h];
      }
    }
  }
  #pragma unroll
  for (int o = 0; o < O_SZ; ++o) {
    float v = acc[o];
    #pragma unroll
    for (int off = 32; off > 0; off >>= 1) v += __shfl_down(v, off);
    if (lane == 0) cur2[(size_t)m * O_SZ + o] = v;
  }
}

// ---------------------------------------------------------------------------
// Phase 2c: layer-2 scan + write outputs (fp32).
// out = [ spk_rec[T,B,O] | mem_rec[T,B,O] ]  (float32)
// ---------------------------------------------------------------------------
__global__ __launch_bounds__(256)
void scan2_kernel(const float* __restrict__ cur2,   // [B*T, O]
                  const float* __restrict__ b2,
                  const float* __restrict__ beta_p,
                  float* __restrict__ out)
{
  const int idx = blockIdx.x * 256 + threadIdx.x;
  if (idx >= B_SZ * O_SZ) return;
  const int b = idx / O_SZ;
  const int o = idx % O_SZ;
  const float beta = beta_p[0];
  const float bias = b2[o];
  float* spk_rec = out;
  float* mem_rec = out + (size_t)T_STEPS * B_SZ * O_SZ;
  float mem = 0.f, spk = 0.f;
  for (int t = 0; t < T_STEPS; ++t) {
    const float cur = cur2[((size_t)b * T_STEPS + t) * O_SZ + o] + bias;
    mem = beta * mem + cur - spk;
    spk = (mem > 1.0f) ? 1.0f : 0.0f;
    const size_t oi = ((size_t)t * B_SZ + b) * O_SZ + o;
    spk_rec[oi] = spk;
    mem_rec[oi] = mem;
  }
}

// ---------------------------------------------------------------------------
extern "C" void kernel_launch(void* const* d_in, const int* in_sizes, int n_in,
                              void* d_out, int out_size, void* d_ws, size_t ws_size,
                              hipStream_t stream)
{
  // ALL inputs/outputs are float32 per the reference dtypes.
  const float* data = (const float*)d_in[0]; // [B,T,2,34,34] -> [25600, 2312]
  const float* w1   = (const float*)d_in[1]; // [1000, 2312]
  const float* b1   = (const float*)d_in[2]; // [1000]
  const float* w2   = (const float*)d_in[3]; // [10, 1000]
  const float* b2   = (const float*)d_in[4]; // [10]
  const float* beta = (const float*)d_in[5]; // [1]
  float* out = (float*)d_out;                // 2 * [100,256,10] fp32

  // Batch-chunked pipeline so ws footprint adapts to ws_size.
  // Per chunk (Bc = B/C): cur1 fp32 [Bc*T,H], spk1 bf16 [Bc*T,H].
  // Full-size cur2 fp32 [B*T,O] (1.02 MB) persists across chunks.
  const size_t s3 = (size_t)B_SZ * T_STEPS * O_SZ * 4;
  int C = 1;
  size_t s1 = 0, s2 = 0;
  for (; C <= 256; C *= 2) {
    const size_t bc = B_SZ / C;
    s1 = bc * T_STEPS * H_SZ * 4;
    s2 = bc * T_STEPS * H_SZ * 2;
    if (s1 + s2 + s3 + 256 <= ws_size) break;
  }
  if (C > 256) {
    C = 256;
    s1 = (size_t)1 * T_STEPS * H_SZ * 4;
    s2 = (size_t)1 * T_STEPS * H_SZ * 2;
  }

  char* ws = (char*)d_ws;
  float*          cur1 = (float*)ws;
  __hip_bfloat16* spk1 = (__hip_bfloat16*)(ws + s1);
  float*          cur2 = (float*)(ws + ((s1 + s2 + 255) & ~(size_t)255));

  const int Bc = B_SZ / C;
  const int Mc = Bc * T_STEPS;

  for (int c = 0; c < C; ++c) {
    const int b0 = c * Bc;
    const float* Ac = data + (size_t)b0 * T_STEPS * D_IN;
    gemm1_f32<<<dim3((Mc + 63) / 64, (H_SZ + 63) / 64), 256, 0, stream>>>(
        Ac, w1, b1, cur1, Mc);
    scan1_kernel<<<dim3(4, Bc), 256, 0, stream>>>(cur1, beta, spk1);
    gemm2_kernel<<<dim3(Mc / 4), 256, 0, stream>>>(
        spk1, w2, cur2 + (size_t)b0 * T_STEPS * O_SZ);
  }
  scan2_kernel<<<dim3(10), 256, 0, stream>>>(cur2, b2, beta, out);
}

// Round 5
// 1065.777 us; speedup vs baseline: 2.0417x; 2.0417x over previous
//
#include <hip/hip_runtime.h>
#include <hip/hip_bf16.h>
#include <stdint.h>

// Problem dims (hardcoded from reference):
// B=256, T=100, D=2*34*34=2312, H=1000, O=10.  ALL tensors fp32.
#define T_STEPS 100
#define B_SZ    256
#define D_IN    2312
#define H_SZ    1000
#define O_SZ    10
#define K_PAD   2336          // 73 * 32 (zero-padded K so the GEMM loop is uniform)
#define KT      73
#define W_ROWS  1024          // H padded to 1024 rows (rows >= 1000 zeroed)

// fp16 split scaling: keeps lo-parts out of the f16 subnormal range.
// A*16 (|a|<6 -> |a'|<96), W*64 (|w|<0.021 -> |w'|<1.34).  acc scale = 1/1024.
#define A_SCALE   16.0f
#define W_SCALE   64.0f
#define INV_SCALE (1.0f / 1024.0f)

typedef __attribute__((ext_vector_type(4))) float     floatx4;
typedef __attribute__((ext_vector_type(8))) _Float16  halfx8;

#define ASYNC_COPY16(g, l)                                             \
  __builtin_amdgcn_global_load_lds(                                    \
      (const __attribute__((address_space(1))) void*)(g),              \
      (__attribute__((address_space(3))) void*)(l), 16, 0, 0)

// ---------------------------------------------------------------------------
// Split fp32 -> f16 hi + f16 lo (lo = f16(x*scale - float(hi))), scaled.
// Output rows padded to K_PAD columns with zeros.
// ---------------------------------------------------------------------------
__device__ inline void split8(const float* __restrict__ src, bool valid,
                              float scale,
                              _Float16* __restrict__ ho,
                              _Float16* __restrict__ lo)
{
  _Float16 h[8], l[8];
  #pragma unroll
  for (int e = 0; e < 8; ++e) {
    const float v = valid ? src[e] * scale : 0.f;
    const _Float16 hb = (_Float16)v;
    h[e] = hb;
    l[e] = (_Float16)(v - (float)hb);
  }
  *reinterpret_cast<uint4*>(ho) = *reinterpret_cast<const uint4*>(h);
  *reinterpret_cast<uint4*>(lo) = *reinterpret_cast<const uint4*>(l);
}

__global__ __launch_bounds__(256)
void splitA_kernel(const float* __restrict__ A,    // [rows, D_IN]
                   _Float16* __restrict__ aHi,     // [rows, K_PAD]
                   _Float16* __restrict__ aLo)
{
  const int r = blockIdx.x;
  const float* a = A + (size_t)r * D_IN;
  _Float16* ho = aHi + (size_t)r * K_PAD;
  _Float16* lo = aLo + (size_t)r * K_PAD;
  for (int c = threadIdx.x; c < K_PAD / 8; c += 256) {
    const int k0 = c * 8;
    split8(a + k0, (k0 + 8 <= D_IN), A_SCALE, ho + k0, lo + k0);  // 2312/8=289 full chunks
  }
}

__global__ __launch_bounds__(256)
void splitW_kernel(const float* __restrict__ W,    // [H_SZ, D_IN]
                   _Float16* __restrict__ wHi,     // [W_ROWS, K_PAD]
                   _Float16* __restrict__ wLo)
{
  const int r = blockIdx.x;
  const bool rvalid = (r < H_SZ);
  const float* w = W + (size_t)(rvalid ? r : 0) * D_IN;
  _Float16* ho = wHi + (size_t)r * K_PAD;
  _Float16* lo = wLo + (size_t)r * K_PAD;
  for (int c = threadIdx.x; c < K_PAD / 8; c += 256) {
    const int k0 = c * 8;
    split8(w + k0, rvalid && (k0 + 8 <= D_IN), W_SCALE, ho + k0, lo + k0);
  }
}

// ---------------------------------------------------------------------------
// Phase 1: cur1[m][n] = (sum_k A'[m][k]*W'[n][k]) / 1024 + b1[n],
// split-f16 3-pass MFMA: acc += Ah*Bh + Al*Bh + Ah*Bl.
// m97 structure: 128x128 tile, BK=32, 4 waves of 64x64, global_load_lds
// staging (width 16), mfma_f32_16x16x32_f16.  K pre-padded -> uniform loop.
// ---------------------------------------------------------------------------
__global__ __launch_bounds__(256)
void gemm1_mfma(const _Float16* __restrict__ aHi,  // [Mc, K_PAD]
                const _Float16* __restrict__ aLo,
                const _Float16* __restrict__ wHi,  // [W_ROWS, K_PAD]
                const _Float16* __restrict__ wLo,
                const float* __restrict__ b1,      // [H_SZ]
                float* __restrict__ C)             // [Mc, H_SZ]
{
  __shared__ _Float16 sAh[128 * 32];
  __shared__ _Float16 sAl[128 * 32];
  __shared__ _Float16 sBh[128 * 32];
  __shared__ _Float16 sBl[128 * 32];

  const int tid  = threadIdx.x;
  const int n0   = blockIdx.x * 128;   // x = n-tiles fastest -> A slab L2 reuse
  const int m0   = blockIdx.y * 128;
  const int wid  = tid >> 6;
  const int lane = tid & 63;
  const int wm   = (wid & 1) * 64;
  const int wn   = (wid >> 1) * 64;
  const int quad = lane >> 4;
  const int l16  = lane & 15;

  floatx4 acc[4][4];
  #pragma unroll
  for (int i = 0; i < 4; ++i)
    #pragma unroll
    for (int j = 0; j < 4; ++j)
      acc[i][j] = floatx4{0.f, 0.f, 0.f, 0.f};

  // m97 staging map: thread tid stages 16B chunk tid (rows 0..63) and
  // tid+256 (rows 64..127); LDS dest = base + tid*16 (wave-uniform + lane*16).
  const int r0 = tid >> 2;
  const int r1 = r0 + 64;
  const int ko = (tid & 3) * 8;

  const _Float16* gAh0 = aHi + (size_t)(m0 + r0) * K_PAD + ko;
  const _Float16* gAh1 = aHi + (size_t)(m0 + r1) * K_PAD + ko;
  const _Float16* gAl0 = aLo + (size_t)(m0 + r0) * K_PAD + ko;
  const _Float16* gAl1 = aLo + (size_t)(m0 + r1) * K_PAD + ko;
  const _Float16* gBh0 = wHi + (size_t)(n0 + r0) * K_PAD + ko;
  const _Float16* gBh1 = wHi + (size_t)(n0 + r1) * K_PAD + ko;
  const _Float16* gBl0 = wLo + (size_t)(n0 + r0) * K_PAD + ko;
  const _Float16* gBl1 = wLo + (size_t)(n0 + r1) * K_PAD + ko;

  _Float16* lAh0 = sAh + (size_t)tid * 8;
  _Float16* lAh1 = sAh + (size_t)(tid + 256) * 8;
  _Float16* lAl0 = sAl + (size_t)tid * 8;
  _Float16* lAl1 = sAl + (size_t)(tid + 256) * 8;
  _Float16* lBh0 = sBh + (size_t)tid * 8;
  _Float16* lBh1 = sBh + (size_t)(tid + 256) * 8;
  _Float16* lBl0 = sBl + (size_t)tid * 8;
  _Float16* lBl1 = sBl + (size_t)(tid + 256) * 8;

  for (int kt = 0; kt < KT; ++kt) {
    const int koff = kt * 32;
    __syncthreads();                       // previous tile's LDS reads done
    ASYNC_COPY16(gAh0 + koff, lAh0);
    ASYNC_COPY16(gAh1 + koff, lAh1);
    ASYNC_COPY16(gAl0 + koff, lAl0);
    ASYNC_COPY16(gAl1 + koff, lAl1);
    ASYNC_COPY16(gBh0 + koff, lBh0);
    ASYNC_COPY16(gBh1 + koff, lBh1);
    ASYNC_COPY16(gBl0 + koff, lBl0);
    ASYNC_COPY16(gBl1 + koff, lBl1);
    __syncthreads();                       // vmcnt drained before barrier

    halfx8 ah[4], bh[4], al[4], bl[4];
    #pragma unroll
    for (int i = 0; i < 4; ++i) {
      const int row = (wm + i * 16 + l16) * 32 + quad * 8;
      ah[i] = *reinterpret_cast<const halfx8*>(sAh + row);
      al[i] = *reinterpret_cast<const halfx8*>(sAl + row);
    }
    #pragma unroll
    for (int j = 0; j < 4; ++j) {
      const int row = (wn + j * 16 + l16) * 32 + quad * 8;
      bh[j] = *reinterpret_cast<const halfx8*>(sBh + row);
      bl[j] = *reinterpret_cast<const halfx8*>(sBl + row);
    }
    #pragma unroll
    for (int i = 0; i < 4; ++i)
      #pragma unroll
      for (int j = 0; j < 4; ++j)
        acc[i][j] = __builtin_amdgcn_mfma_f32_16x16x32_f16(ah[i], bh[j], acc[i][j], 0, 0, 0);
    #pragma unroll
    for (int i = 0; i < 4; ++i)
      #pragma unroll
      for (int j = 0; j < 4; ++j)
        acc[i][j] = __builtin_amdgcn_mfma_f32_16x16x32_f16(al[i], bh[j], acc[i][j], 0, 0, 0);
    #pragma unroll
    for (int i = 0; i < 4; ++i)
      #pragma unroll
      for (int j = 0; j < 4; ++j)
        acc[i][j] = __builtin_amdgcn_mfma_f32_16x16x32_f16(ah[i], bl[j], acc[i][j], 0, 0, 0);
  }

  // Epilogue: C/D layout col = lane&15, row = quad*4 + reg (m89/m91 verified).
  // Unscale by exact power of two, then add bias.
  #pragma unroll
  for (int j = 0; j < 4; ++j) {
    const int col = n0 + wn + j * 16 + l16;
    if (col < H_SZ) {
      const float bias = b1[col];
      #pragma unroll
      for (int i = 0; i < 4; ++i) {
        const int row = m0 + wm + i * 16 + quad * 4;
        #pragma unroll
        for (int r = 0; r < 4; ++r)
          C[(size_t)(row + r) * H_SZ + col] = acc[i][j][r] * INV_SCALE + bias;
      }
    }
  }
}

// ---------------------------------------------------------------------------
// Phase 2a: layer-1 LIF scan. One thread per (b,h) chain.
// ---------------------------------------------------------------------------
__global__ __launch_bounds__(256)
void scan1_kernel(const float* __restrict__ cur1,     // [Bc, T, H] fp32
                  const float* __restrict__ beta_p,
                  __hip_bfloat16* __restrict__ spk1)  // [Bc, T, H] bf16 (0/1)
{
  const int h = blockIdx.x * 256 + threadIdx.x;
  const int b = blockIdx.y;
  if (h >= H_SZ) return;
  const float beta = beta_p[0];
  const float* c    = cur1 + (size_t)b * T_STEPS * H_SZ + h;
  __hip_bfloat16* s = spk1 + (size_t)b * T_STEPS * H_SZ + h;
  float mem = 0.f, spk = 0.f;
  #pragma unroll 4
  for (int t = 0; t < T_STEPS; ++t) {
    mem = beta * mem + c[(size_t)t * H_SZ] - spk;
    spk = (mem > 1.0f) ? 1.0f : 0.0f;
    s[(size_t)t * H_SZ] = __float2bfloat16(spk);
  }
}

// ---------------------------------------------------------------------------
// Phase 2b: cur2[m][o] = sum_h spk1[m][h] * w2[o][h].  Wave per row m.
// Spikes are exactly 0/1 -> accumulate w2 where spike!=0 (exact).
// ---------------------------------------------------------------------------
__global__ __launch_bounds__(256)
void gemm2_kernel(const __hip_bfloat16* __restrict__ spk1, // [Mc, H]
                  const float* __restrict__ w2,            // [O, H] fp32
                  float* __restrict__ cur2)                // [Mc, O] slice
{
  const int wid  = threadIdx.x >> 6;
  const int lane = threadIdx.x & 63;
  const int m    = blockIdx.x * 4 + wid;

  float acc[O_SZ];
  #pragma unroll
  for (int o = 0; o < O_SZ; ++o) acc[o] = 0.f;

  const __hip_bfloat16* row = spk1 + (size_t)m * H_SZ;
  #pragma unroll
  for (int it = 0; it < 16; ++it) {
    const int h = it * 64 + lane;
    if (h < H_SZ) {
      const float s = __bfloat162float(row[h]);
      if (s != 0.f) {
        #pragma unroll
        for (int o = 0; o < O_SZ; ++o)
          acc[o] += w2[o * H_SZ + h];
      }
    }
  }
  #pragma unroll
  for (int o = 0; o < O_SZ; ++o) {
    float v = acc[o];
    #pragma unroll
    for (int off = 32; off > 0; off >>= 1) v += __shfl_down(v, off);
    if (lane == 0) cur2[(size_t)m * O_SZ + o] = v;
  }
}

// ---------------------------------------------------------------------------
// Phase 2c: layer-2 scan + write outputs (fp32).
// ---------------------------------------------------------------------------
__global__ __launch_bounds__(256)
void scan2_kernel(const float* __restrict__ cur2,   // [B*T, O]
                  const float* __restrict__ b2,
                  const float* __restrict__ beta_p,
                  float* __restrict__ out)
{
  const int idx = blockIdx.x * 256 + threadIdx.x;
  if (idx >= B_SZ * O_SZ) return;
  const int b = idx / O_SZ;
  const int o = idx % O_SZ;
  const float beta = beta_p[0];
  const float bias = b2[o];
  float* spk_rec = out;
  float* mem_rec = out + (size_t)T_STEPS * B_SZ * O_SZ;
  float mem = 0.f, spk = 0.f;
  for (int t = 0; t < T_STEPS; ++t) {
    const float cur = cur2[((size_t)b * T_STEPS + t) * O_SZ + o] + bias;
    mem = beta * mem + cur - spk;
    spk = (mem > 1.0f) ? 1.0f : 0.0f;
    const size_t oi = ((size_t)t * B_SZ + b) * O_SZ + o;
    spk_rec[oi] = spk;
    mem_rec[oi] = mem;
  }
}

// ---------------------------------------------------------------------------
extern "C" void kernel_launch(void* const* d_in, const int* in_sizes, int n_in,
                              void* d_out, int out_size, void* d_ws, size_t ws_size,
                              hipStream_t stream)
{
  const float* data = (const float*)d_in[0]; // [B,T,2,34,34] -> [25600, 2312]
  const float* w1   = (const float*)d_in[1]; // [1000, 2312]
  const float* b1   = (const float*)d_in[2]; // [1000]
  const float* w2   = (const float*)d_in[3]; // [10, 1000]
  const float* b2   = (const float*)d_in[4]; // [10]
  const float* beta = (const float*)d_in[5]; // [1]
  float* out = (float*)d_out;                // 2 * [100,256,10] fp32

  // Workspace (batch-chunked; ws_size >= ~156 MB observed -> picks C=4):
  //   static : wHi, wLo f16 [1024, K_PAD], cur2 fp32 [B*T, O]
  //   chunked: aHi, aLo f16 [Mc, K_PAD], cur1 fp32 [Mc, H], spk1 bf16 [Mc, H]
  const size_t wS  = (size_t)W_ROWS * K_PAD * 2;
  const size_t c2S = (size_t)B_SZ * T_STEPS * O_SZ * 4;
  int C = 1;
  size_t aS = 0, c1S = 0, s1S = 0;
  for (; C <= 8; C *= 2) {
    const size_t Mc = (size_t)(B_SZ / C) * T_STEPS;
    aS  = Mc * K_PAD * 2;
    c1S = Mc * H_SZ * 4;
    s1S = Mc * H_SZ * 2;
    if (2 * wS + c2S + 2 * aS + c1S + s1S + 4096 <= ws_size) break;
  }
  if (C > 8) {
    C = 8;
    const size_t Mc = (size_t)(B_SZ / C) * T_STEPS;
    aS = Mc * K_PAD * 2; c1S = Mc * H_SZ * 4; s1S = Mc * H_SZ * 2;
  }

  char* p = (char*)d_ws;
  auto take = [&](size_t n) { char* q = p; p += (n + 255) & ~(size_t)255; return q; };
  _Float16*       wHi  = (_Float16*)take(wS);
  _Float16*       wLo  = (_Float16*)take(wS);
  float*          cur2 = (float*)take(c2S);
  _Float16*       aHi  = (_Float16*)take(aS);
  _Float16*       aLo  = (_Float16*)take(aS);
  float*          cur1 = (float*)take(c1S);
  __hip_bfloat16* spk1 = (__hip_bfloat16*)take(s1S);

  const int Bc = B_SZ / C;
  const int Mc = Bc * T_STEPS;   // divisible by 128 for C in {1,2,4,8}

  splitW_kernel<<<dim3(W_ROWS), 256, 0, stream>>>(w1, wHi, wLo);

  for (int c = 0; c < C; ++c) {
    const int b0 = c * Bc;
    const float* Ac = data + (size_t)b0 * T_STEPS * D_IN;
    splitA_kernel<<<dim3(Mc), 256, 0, stream>>>(Ac, aHi, aLo);
    gemm1_mfma<<<dim3(8, Mc / 128), 256, 0, stream>>>(aHi, aLo, wHi, wLo, b1, cur1);
    scan1_kernel<<<dim3(4, Bc), 256, 0, stream>>>(cur1, beta, spk1);
    gemm2_kernel<<<dim3(Mc / 4), 256, 0, stream>>>(
        spk1, w2, cur2 + (size_t)b0 * T_STEPS * O_SZ);
  }
  scan2_kernel<<<dim3(10), 256, 0, stream>>>(cur2, b2, beta, out);
}

// Round 6
// 884.691 us; speedup vs baseline: 2.4596x; 1.2047x over previous
//
#include <hip/hip_runtime.h>
#include <hip/hip_bf16.h>
#include <stdint.h>

// Problem dims (hardcoded from reference):
// B=256, T=100, D=2*34*34=2312, H=1000, O=10.  ALL tensors fp32.
#define T_STEPS 100
#define B_SZ    256
#define D_IN    2312
#define H_SZ    1000
#define O_SZ    10
#define M_ROWS  (B_SZ * T_STEPS)   // 25600
#define K_PAD   2336               // 73 * 32 (W pre-split padded)
#define KT      73
#define W_ROWS  1024               // H padded to 1024 rows (rows >= 1000 zeroed)

// fp16 split scaling keeps lo-parts out of f16 subnormals.
// A*16 (|a|<6), W*64 (|w|<0.022).  Epilogue scale = 1/1024 (exact pow2).
#define A_SCALE   16.0f
#define W_SCALE   64.0f
#define INV_SCALE (1.0f / 1024.0f)

typedef __attribute__((ext_vector_type(4))) float     floatx4;
typedef __attribute__((ext_vector_type(8))) _Float16  halfx8;

#define ASYNC_COPY16(g, l)                                             \
  __builtin_amdgcn_global_load_lds(                                    \
      (const __attribute__((address_space(1))) void*)(g),              \
      (__attribute__((address_space(3))) void*)(l), 16, 0, 0)

// ---------------------------------------------------------------------------
// W pre-split: fp32 -> f16 hi/lo, scaled by 64, rows padded to K_PAD/W_ROWS.
// ---------------------------------------------------------------------------
__global__ __launch_bounds__(256)
void splitW_kernel(const float* __restrict__ W,    // [H_SZ, D_IN]
                   _Float16* __restrict__ wHi,     // [W_ROWS, K_PAD]
                   _Float16* __restrict__ wLo)
{
  const int r = blockIdx.x;
  const bool rvalid = (r < H_SZ);
  const float* w = W + (size_t)(rvalid ? r : 0) * D_IN;
  _Float16* ho = wHi + (size_t)r * K_PAD;
  _Float16* lo = wLo + (size_t)r * K_PAD;
  for (int c = threadIdx.x; c < K_PAD / 8; c += 256) {
    const int k0 = c * 8;
    const bool v = rvalid && (k0 + 8 <= D_IN);
    _Float16 h[8], l[8];
    #pragma unroll
    for (int e = 0; e < 8; ++e) {
      const float x = v ? w[k0 + e] * W_SCALE : 0.f;
      const _Float16 hb = (_Float16)x;
      h[e] = hb;
      l[e] = (_Float16)(x - (float)hb);
    }
    *reinterpret_cast<uint4*>(ho + k0) = *reinterpret_cast<const uint4*>(h);
    *reinterpret_cast<uint4*>(lo + k0) = *reinterpret_cast<const uint4*>(l);
  }
}

// ---------------------------------------------------------------------------
// Phase 1 (fused): cur1 = (A*16 fp32->f16split @ Wsplit) / 1024 + b1.
// m97 128x128 tile, BK=32, 4 waves 64x64, 3-pass split-f16 MFMA.
// NEW vs r5: (1) XOR bank swizzle — row r's 16B chunk q lives at slot
// q ^ ((r>>1)&3), making ds_read_b128 phases hit all 8 bank-quads;
// (2) A staged from raw fp32 with in-register split + ds_write (splitA
// kernel eliminated), prefetched one k-tile ahead so the global latency
// overlaps the MFMA phase.
// ---------------------------------------------------------------------------
__global__ __launch_bounds__(256)
void gemm1_fused(const float* __restrict__ A,       // [M_ROWS, D_IN] fp32
                 const _Float16* __restrict__ wHi,  // [W_ROWS, K_PAD]
                 const _Float16* __restrict__ wLo,
                 const float* __restrict__ b1,      // [H_SZ]
                 float* __restrict__ C)             // [M_ROWS, H_SZ]
{
  __shared__ _Float16 sAh[128 * 32];
  __shared__ _Float16 sAl[128 * 32];
  __shared__ _Float16 sBh[128 * 32];
  __shared__ _Float16 sBl[128 * 32];

  const int tid  = threadIdx.x;
  const int n0   = blockIdx.x * 128;   // x = n-tiles fastest -> A slab L2 reuse
  const int m0   = blockIdx.y * 128;
  const int wid  = tid >> 6;
  const int lane = tid & 63;
  const int wm   = (wid & 1) * 64;
  const int wn   = (wid >> 1) * 64;
  const int quad = lane >> 4;
  const int l16  = lane & 15;

  floatx4 acc[4][4];
  #pragma unroll
  for (int i = 0; i < 4; ++i)
    #pragma unroll
    for (int j = 0; j < 4; ++j)
      acc[i][j] = floatx4{0.f, 0.f, 0.f, 0.f};

  // Staging map: thread tid owns rows r0=tid>>2 and r1=r0+64, LDS slot tid&3.
  // Swizzle: slot s of row r holds global chunk s ^ rho(r), rho(r)=(r>>1)&3.
  // (rho(r0)==rho(r0+64), so one ko serves both rows.)
  const int r0  = tid >> 2;
  const int r1  = r0 + 64;
  const int sl  = tid & 3;
  const int rho = (r0 >> 1) & 3;
  const int ko  = ((sl ^ rho) * 8);   // swizzled global chunk offset (elements)

  const float* gA0 = A + (size_t)(m0 + r0) * D_IN + ko;
  const float* gA1 = A + (size_t)(m0 + r1) * D_IN + ko;
  const _Float16* gBh0 = wHi + (size_t)(n0 + r0) * K_PAD + ko;
  const _Float16* gBh1 = wHi + (size_t)(n0 + r1) * K_PAD + ko;
  const _Float16* gBl0 = wLo + (size_t)(n0 + r0) * K_PAD + ko;
  const _Float16* gBl1 = wLo + (size_t)(n0 + r1) * K_PAD + ko;

  _Float16* lAh0 = sAh + (size_t)tid * 8;
  _Float16* lAh1 = sAh + (size_t)(tid + 256) * 8;
  _Float16* lAl0 = sAl + (size_t)tid * 8;
  _Float16* lAl1 = sAl + (size_t)(tid + 256) * 8;
  _Float16* lBh0 = sBh + (size_t)tid * 8;
  _Float16* lBh1 = sBh + (size_t)(tid + 256) * 8;
  _Float16* lBl0 = sBl + (size_t)tid * 8;
  _Float16* lBl1 = sBl + (size_t)(tid + 256) * 8;

  // Fragment-read swizzle offset (elements): chunk quad of row wm/wn+i*16+l16
  // lives at slot quad ^ ((l16>>1)&3)  (tile base is a multiple of 16).
  const int fo = (quad ^ ((l16 >> 1) & 3)) * 8;

  // Prefetch A chunks for kt=0 (always in-bounds: ko+8 <= 32 < D_IN).
  float a0[8], a1[8];
  *reinterpret_cast<float4*>(a0)     = *reinterpret_cast<const float4*>(gA0);
  *reinterpret_cast<float4*>(a0 + 4) = *reinterpret_cast<const float4*>(gA0 + 4);
  *reinterpret_cast<float4*>(a1)     = *reinterpret_cast<const float4*>(gA1);
  *reinterpret_cast<float4*>(a1 + 4) = *reinterpret_cast<const float4*>(gA1 + 4);

  for (int kt = 0; kt < KT; ++kt) {
    const int koff = kt * 32;
    __syncthreads();                     // prev tile's LDS reads done (also
                                         // drains the A prefetch issued below)
    ASYNC_COPY16(gBh0 + koff, lBh0);
    ASYNC_COPY16(gBh1 + koff, lBh1);
    ASYNC_COPY16(gBl0 + koff, lBl0);
    ASYNC_COPY16(gBl1 + koff, lBl1);

    // In-register split of the prefetched A chunks, then LDS store.
    {
      _Float16 h0[8], l0[8], h1[8], l1[8];
      #pragma unroll
      for (int e = 0; e < 8; ++e) {
        const float v0 = a0[e] * A_SCALE;
        const _Float16 hb0 = (_Float16)v0;
        h0[e] = hb0; l0[e] = (_Float16)(v0 - (float)hb0);
        const float v1 = a1[e] * A_SCALE;
        const _Float16 hb1 = (_Float16)v1;
        h1[e] = hb1; l1[e] = (_Float16)(v1 - (float)hb1);
      }
      *reinterpret_cast<uint4*>(lAh0) = *reinterpret_cast<const uint4*>(h0);
      *reinterpret_cast<uint4*>(lAl0) = *reinterpret_cast<const uint4*>(l0);
      *reinterpret_cast<uint4*>(lAh1) = *reinterpret_cast<const uint4*>(h1);
      *reinterpret_cast<uint4*>(lAl1) = *reinterpret_cast<const uint4*>(l1);
    }
    __syncthreads();                     // W DMA (vmcnt) + A ds_write (lgkm)

    // Prefetch A for kt+1 — outstanding across the MFMA phase below.
    if (kt + 1 < KT) {
      const int k = (kt + 1) * 32 + ko;
      if (k < D_IN) {                    // D_IN%8==0 -> full chunk in-bounds
        *reinterpret_cast<float4*>(a0)     = *reinterpret_cast<const float4*>(gA0 + (kt + 1) * 32);
        *reinterpret_cast<float4*>(a0 + 4) = *reinterpret_cast<const float4*>(gA0 + (kt + 1) * 32 + 4);
        *reinterpret_cast<float4*>(a1)     = *reinterpret_cast<const float4*>(gA1 + (kt + 1) * 32);
        *reinterpret_cast<float4*>(a1 + 4) = *reinterpret_cast<const float4*>(gA1 + (kt + 1) * 32 + 4);
      } else {
        #pragma unroll
        for (int e = 0; e < 8; ++e) { a0[e] = 0.f; a1[e] = 0.f; }
      }
    }

    halfx8 ah[4], bh[4], al[4], bl[4];
    #pragma unroll
    for (int i = 0; i < 4; ++i) {
      const int row = (wm + i * 16 + l16) * 32 + fo;
      ah[i] = *reinterpret_cast<const halfx8*>(sAh + row);
      al[i] = *reinterpret_cast<const halfx8*>(sAl + row);
    }
    #pragma unroll
    for (int j = 0; j < 4; ++j) {
      const int row = (wn + j * 16 + l16) * 32 + fo;
      bh[j] = *reinterpret_cast<const halfx8*>(sBh + row);
      bl[j] = *reinterpret_cast<const halfx8*>(sBl + row);
    }
    #pragma unroll
    for (int i = 0; i < 4; ++i)
      #pragma unroll
      for (int j = 0; j < 4; ++j)
        acc[i][j] = __builtin_amdgcn_mfma_f32_16x16x32_f16(ah[i], bh[j], acc[i][j], 0, 0, 0);
    #pragma unroll
    for (int i = 0; i < 4; ++i)
      #pragma unroll
      for (int j = 0; j < 4; ++j)
        acc[i][j] = __builtin_amdgcn_mfma_f32_16x16x32_f16(al[i], bh[j], acc[i][j], 0, 0, 0);
    #pragma unroll
    for (int i = 0; i < 4; ++i)
      #pragma unroll
      for (int j = 0; j < 4; ++j)
        acc[i][j] = __builtin_amdgcn_mfma_f32_16x16x32_f16(ah[i], bl[j], acc[i][j], 0, 0, 0);
  }

  // Epilogue: C/D layout col = lane&15, row = quad*4 + reg (m89/m91 verified).
  #pragma unroll
  for (int j = 0; j < 4; ++j) {
    const int col = n0 + wn + j * 16 + l16;
    if (col < H_SZ) {
      const float bias = b1[col];
      #pragma unroll
      for (int i = 0; i < 4; ++i) {
        const int row = m0 + wm + i * 16 + quad * 4;
        #pragma unroll
        for (int r = 0; r < 4; ++r)
          C[(size_t)(row + r) * H_SZ + col] = acc[i][j][r] * INV_SCALE + bias;
      }
    }
  }
}

// ---------------------------------------------------------------------------
// Phase 2a: layer-1 LIF scan. One thread per (b,h) chain.
// ---------------------------------------------------------------------------
__global__ __launch_bounds__(256)
void scan1_kernel(const float* __restrict__ cur1,     // [B, T, H] fp32
                  const float* __restrict__ beta_p,
                  __hip_bfloat16* __restrict__ spk1)  // [B, T, H] bf16 (0/1)
{
  const int h = blockIdx.x * 256 + threadIdx.x;
  const int b = blockIdx.y;
  if (h >= H_SZ) return;
  const float beta = beta_p[0];
  const float* c    = cur1 + (size_t)b * T_STEPS * H_SZ + h;
  __hip_bfloat16* s = spk1 + (size_t)b * T_STEPS * H_SZ + h;
  float mem = 0.f, spk = 0.f;
  #pragma unroll 4
  for (int t = 0; t < T_STEPS; ++t) {
    mem = beta * mem + c[(size_t)t * H_SZ] - spk;
    spk = (mem > 1.0f) ? 1.0f : 0.0f;
    s[(size_t)t * H_SZ] = __float2bfloat16(spk);
  }
}

// ---------------------------------------------------------------------------
// Phase 2b: cur2[m][o] = sum_h spk1[m][h] * w2[o][h].  Wave per row m.
// Spikes are exactly 0/1 -> accumulate w2 where spike!=0 (exact).
// ---------------------------------------------------------------------------
__global__ __launch_bounds__(256)
void gemm2_kernel(const __hip_bfloat16* __restrict__ spk1, // [M_ROWS, H]
                  const float* __restrict__ w2,            // [O, H] fp32
                  float* __restrict__ cur2)                // [M_ROWS, O]
{
  const int wid  = threadIdx.x >> 6;
  const int lane = threadIdx.x & 63;
  const int m    = blockIdx.x * 4 + wid;

  float acc[O_SZ];
  #pragma unroll
  for (int o = 0; o < O_SZ; ++o) acc[o] = 0.f;

  const __hip_bfloat16* row = spk1 + (size_t)m * H_SZ;
  #pragma unroll
  for (int it = 0; it < 16; ++it) {
    const int h = it * 64 + lane;
    if (h < H_SZ) {
      const float s = __bfloat162float(row[h]);
      if (s != 0.f) {
        #pragma unroll
        for (int o = 0; o < O_SZ; ++o)
          acc[o] += w2[o * H_SZ + h];
      }
    }
  }
  #pragma unroll
  for (int o = 0; o < O_SZ; ++o) {
    float v = acc[o];
    #pragma unroll
    for (int off = 32; off > 0; off >>= 1) v += __shfl_down(v, off);
    if (lane == 0) cur2[(size_t)m * O_SZ + o] = v;
  }
}

// ---------------------------------------------------------------------------
// Phase 2c: layer-2 scan + write outputs (fp32).
// ---------------------------------------------------------------------------
__global__ __launch_bounds__(256)
void scan2_kernel(const float* __restrict__ cur2,   // [B*T, O]
                  const float* __restrict__ b2,
                  const float* __restrict__ beta_p,
                  float* __restrict__ out)
{
  const int idx = blockIdx.x * 256 + threadIdx.x;
  if (idx >= B_SZ * O_SZ) return;
  const int b = idx / O_SZ;
  const int o = idx % O_SZ;
  const float beta = beta_p[0];
  const float bias = b2[o];
  float* spk_rec = out;
  float* mem_rec = out + (size_t)T_STEPS * B_SZ * O_SZ;
  float mem = 0.f, spk = 0.f;
  for (int t = 0; t < T_STEPS; ++t) {
    const float cur = cur2[((size_t)b * T_STEPS + t) * O_SZ + o] + bias;
    mem = beta * mem + cur - spk;
    spk = (mem > 1.0f) ? 1.0f : 0.0f;
    const size_t oi = ((size_t)t * B_SZ + b) * O_SZ + o;
    spk_rec[oi] = spk;
    mem_rec[oi] = mem;
  }
}

// ---------------------------------------------------------------------------
extern "C" void kernel_launch(void* const* d_in, const int* in_sizes, int n_in,
                              void* d_out, int out_size, void* d_ws, size_t ws_size,
                              hipStream_t stream)
{
  const float* data = (const float*)d_in[0]; // [B,T,2,34,34] -> [25600, 2312]
  const float* w1   = (const float*)d_in[1]; // [1000, 2312]
  const float* b1   = (const float*)d_in[2]; // [1000]
  const float* w2   = (const float*)d_in[3]; // [10, 1000]
  const float* b2   = (const float*)d_in[4]; // [10]
  const float* beta = (const float*)d_in[5]; // [1]
  float* out = (float*)d_out;                // 2 * [100,256,10] fp32

  // Workspace (fixed, ~164 MB; round-5 WRITE_SIZE proved ws_size >= ~327 MB):
  //   wHi, wLo : f16 [1024, 2336]  = 4.78 MB each
  //   cur1     : fp32 [25600,1000] = 102.4 MB
  //   spk1     : bf16 [25600,1000] = 51.2 MB
  //   cur2     : fp32 [25600,10]   = 1.02 MB
  char* p = (char*)d_ws;
  auto take = [&](size_t n) { char* q = p; p += (n + 255) & ~(size_t)255; return q; };
  _Float16*       wHi  = (_Float16*)take((size_t)W_ROWS * K_PAD * 2);
  _Float16*       wLo  = (_Float16*)take((size_t)W_ROWS * K_PAD * 2);
  float*          cur1 = (float*)take((size_t)M_ROWS * H_SZ * 4);
  __hip_bfloat16* spk1 = (__hip_bfloat16*)take((size_t)M_ROWS * H_SZ * 2);
  float*          cur2 = (float*)take((size_t)M_ROWS * O_SZ * 4);

  splitW_kernel<<<dim3(W_ROWS), 256, 0, stream>>>(w1, wHi, wLo);
  gemm1_fused<<<dim3(8, M_ROWS / 128), 256, 0, stream>>>(data, wHi, wLo, b1, cur1);
  scan1_kernel<<<dim3(4, B_SZ), 256, 0, stream>>>(cur1, beta, spk1);
  gemm2_kernel<<<dim3(M_ROWS / 4), 256, 0, stream>>>(spk1, w2, cur2);
  scan2_kernel<<<dim3(10), 256, 0, stream>>>(cur2, b2, beta, out);
}